// Round 10
// baseline (14002.248 us; speedup 1.0000x reference)
//
#include <hip/hip_runtime.h>
#include <hip/hip_bf16.h>

// B=2, S=2048, D=1024, H=16, dk=64. INPUTS FP32, OUTPUT FP32 (threshold
// 0.0314 == 2% of max|ref| => fp32 comparison path; "bf16" in the harness
// label is a hardcoded string). M = B*S = 4096 rows.
// ROUND 10: r9's all-naive pipeline with FP32 d_out writes. Green first.

typedef __bf16 bf16x8 __attribute__((ext_vector_type(8)));

#define LOG2E 1.4426950408889634f

__device__ __forceinline__ ushort f2bf(float f) {
  __hip_bfloat16 h = __float2bfloat16(f);
  return __builtin_bit_cast(ushort, h);
}

// ------------------------------------------------------- naive QKV + RoPE
// One thread = one (m, g, h, dkp) rotation pair; e = g*1024 + h*64 + dkp.
// Computes qkv[m][e], qkv[m][e+32], applies reference RoPE, scatters to
// q/k/v [B,H,S,64] bf16. q pre-scaled by 0.125*log2e (exp2-domain softmax).
__global__ __launch_bounds__(256) void qkv_naive(
    const float* __restrict__ x, const float* __restrict__ Wqkv,
    ushort* __restrict__ qb, ushort* __restrict__ kb, ushort* __restrict__ vb) {
  long idx = (long)blockIdx.x * 256 + threadIdx.x;  // [0, 4096*3*16*32)
  int dkp = (int)(idx & 31);
  long t = idx >> 5;
  int h = (int)(t & 15);
  t >>= 4;                       // t = m*3 + g
  int g = (int)(t % 3);
  int m = (int)(t / 3);

  const float* xr = x + (long)m * 1024;
  const float* w1 = Wqkv + ((long)g * 1024 + h * 64 + dkp) * 1024;
  const float* w2 = w1 + 32 * 1024;
  float s1 = 0.0f, s2 = 0.0f;
  for (int k = 0; k < 1024; k += 4) {
    float4 xa = *(const float4*)(xr + k);
    float4 wa = *(const float4*)(w1 + k);
    float4 wb = *(const float4*)(w2 + k);
    s1 += xa.x * wa.x + xa.y * wa.y + xa.z * wa.z + xa.w * wa.w;
    s2 += xa.x * wb.x + xa.y * wb.y + xa.z * wb.z + xa.w * wb.w;
  }

  int srow = m & 2047, b = m >> 11;
  if (g < 2 && dkp < 16) {  // nonzero freq only for dkp<16 (quarter=16)
    float ang = powf(1e-4f, (float)dkp * (1.0f / 15.0f));
    float theta = (float)srow * ang;
    float sn, c;
    sincosf(theta, &sn, &c);
    float o1 = s1 * c - s2 * sn;
    float o2 = s1 * sn + s2 * c;
    s1 = o1;
    s2 = o2;
  }
  float qs = (g == 0) ? 0.125f * LOG2E : 1.0f;
  ushort* dst = (g == 0) ? qb : ((g == 1) ? kb : vb);
  ushort* drow = dst + (((long)b * 16 + h) * 2048 + srow) * 64;
  drow[dkp] = f2bf(s1 * qs);
  drow[dkp + 32] = f2bf(s2 * qs);
}

// -------------------------------------------------- naive attention (probe)
// One lane = one (bh, row). fp32 dot + online softmax over keys 0..row.
// q pre-scaled by 0.125*log2e -> exp2 domain. Output ao bf16 [m][h*64+dk].
__global__ __launch_bounds__(64) void attn_naive(
    const ushort* __restrict__ qb, const ushort* __restrict__ kb,
    const ushort* __restrict__ vb, ushort* __restrict__ out) {
  const int lane = threadIdx.x;           // 0..63
  const int rt = blockIdx.x;              // 0..31 (64 rows each)
  const int bh = blockIdx.y;              // 0..31
  const int bidx = bh >> 4, h = bh & 15;
  const int row = rt * 64 + lane;         // q row in [0,2048)
  const ushort* Q = qb + ((long)bh * 2048 + row) * 64;
  const ushort* K = kb + (long)bh * 2048 * 64;
  const ushort* V = vb + (long)bh * 2048 * 64;

  float q[64], o[64];
#pragma unroll
  for (int d = 0; d < 64; ++d) {
    q[d] = (float)(*(const __bf16*)&Q[d]);
    o[d] = 0.0f;
  }
  float mm = -3.0e38f, ll = 0.0f;
  for (int key = 0; key <= row; ++key) {
    float s = 0.0f;
#pragma unroll
    for (int c = 0; c < 8; ++c) {
      bf16x8 kv = *(const bf16x8*)&K[key * 64 + c * 8];
#pragma unroll
      for (int e = 0; e < 8; ++e) s += q[c * 8 + e] * (float)kv[e];
    }
    float mn = fmaxf(mm, s);
    float alpha = exp2f(mm - mn);
    float p = exp2f(s - mn);
    mm = mn;
    ll = ll * alpha + p;
#pragma unroll
    for (int c = 0; c < 8; ++c) {
      bf16x8 vv = *(const bf16x8*)&V[key * 64 + c * 8];
#pragma unroll
      for (int e = 0; e < 8; ++e)
        o[c * 8 + e] = o[c * 8 + e] * alpha + p * (float)vv[e];
    }
  }
  float linv = 1.0f / ll;
  long m = (long)bidx * 2048 + row;
  ushort* drow = out + m * 1024 + h * 64;
#pragma unroll
  for (int d = 0; d < 64; ++d) drow[d] = f2bf(o[d] * linv);
}

// ------------------------------------------------------- naive out-proj
// One thread = one out[m][e] = sum_d ao[m][d] * Wo[e][d]. FP32 STORE.
__global__ __launch_bounds__(256) void oproj_naive(
    const ushort* __restrict__ ao, const float* __restrict__ Wo,
    float* __restrict__ out) {
  long idx = (long)blockIdx.x * 256 + threadIdx.x;  // [0, 4096*1024)
  int e = (int)(idx & 1023);
  long m = idx >> 10;
  const ushort* ar = ao + m * 1024;
  const float* wr = Wo + (long)e * 1024;
  float s = 0.0f;
  for (int k = 0; k < 1024; k += 8) {
    bf16x8 av = *(const bf16x8*)(ar + k);
    float4 w0 = *(const float4*)(wr + k);
    float4 w1 = *(const float4*)(wr + k + 4);
    s += (float)av[0] * w0.x + (float)av[1] * w0.y + (float)av[2] * w0.z +
         (float)av[3] * w0.w + (float)av[4] * w1.x + (float)av[5] * w1.y +
         (float)av[6] * w1.z + (float)av[7] * w1.w;
  }
  out[m * 1024 + e] = s;
}

extern "C" void kernel_launch(void* const* d_in, const int* in_sizes, int n_in,
                              void* d_out, int out_size, void* d_ws, size_t ws_size,
                              hipStream_t stream) {
  const float* x = nullptr;     // 4194304 elems
  const float* Wqkv = nullptr;  // 3145728 elems
  const float* Wo = nullptr;    // 1048576 elems
  for (int i = 0; i < n_in; ++i) {
    if (in_sizes[i] == 4194304) x = (const float*)d_in[i];
    else if (in_sizes[i] == 3145728) Wqkv = (const float*)d_in[i];
    else if (in_sizes[i] == 1048576) Wo = (const float*)d_in[i];
  }
  float* out = (float*)d_out;  // [4096,1024] FP32

  ushort* qbuf = (ushort*)d_ws;          // [B,H,S,64] bf16, 8 MiB
  ushort* kbuf = qbuf + 4194304;         // 8 MiB
  ushort* vbuf = kbuf + 4194304;         // 8 MiB
  ushort* ao   = vbuf + 4194304;         // [m][1024] bf16, 8 MiB

  qkv_naive<<<24576, 256, 0, stream>>>(x, Wqkv, qbuf, kbuf, vbuf);
  attn_naive<<<dim3(32, 32), 64, 0, stream>>>(qbuf, kbuf, vbuf, ao);
  oproj_naive<<<16384, 256, 0, stream>>>(ao, Wo, out);
}

// Round 11
// 421.360 us; speedup vs baseline: 33.2311x; 33.2311x over previous
//
#include <hip/hip_runtime.h>
#include <hip/hip_bf16.h>

// B=2, S=2048, D=1024, H=16, dk=64. INPUTS FP32, OUTPUT FP32. M = 4096 rows.
// ROUND 11: restore MFMA pipeline (validated self-consistent vs the passing
// naive r10): 128x128-tile bf16 MFMA GEMMs + flash attention. fp32 C-store.

typedef __bf16 bf16x8 __attribute__((ext_vector_type(8)));
typedef float f32x4 __attribute__((ext_vector_type(4)));

#define LOG2E 1.4426950408889634f

__device__ __forceinline__ ushort f2bf(float f) {
  __hip_bfloat16 h = __float2bfloat16(f);
  return __builtin_bit_cast(ushort, h);
}

__device__ __forceinline__ uint pack2(float a, float b) {
  return (uint)f2bf(a) | ((uint)f2bf(b) << 16);
}

// ---------------------------------------------------------------- GEMM (NT)
// C[m][n] = sum_k A[m][k] * Bt[n][k], K=1024. 128x128 tile, 4 waves of 64x64.
// a_fp32/b_fp32: operand dtype (fp32 converted to bf16 during staging).
// epi==0: QKV epilogue (inline RoPE + q-scale + scatter to q/k/v [B,H,S,64])
// epi==1: fp32 store to Cout [m][n]
__global__ __launch_bounds__(256) void gemm_bt(
    const void* __restrict__ Av, const void* __restrict__ Bv,
    int a_fp32, int b_fp32,
    ushort* __restrict__ qb, ushort* __restrict__ kb, ushort* __restrict__ vb,
    float* __restrict__ Cout, int epi) {
  __shared__ __align__(16) ushort As[128 * 64];
  __shared__ __align__(16) ushort Bs[128 * 64];
  const int tid = threadIdx.x;
  const int w = tid >> 6, lane = tid & 63, quad = lane >> 4, lc = lane & 15;
  const int bm = blockIdx.x, bn = blockIdx.y;
  const int wm = (w & 1) * 64, wn = (w >> 1) * 64;

  f32x4 acc[4][4] = {};

  const float*  Agf = (const float*)Av + (long)bm * 131072;
  const ushort* Agh = (const ushort*)Av + (long)bm * 131072;
  const float*  Bgf = (const float*)Bv + (long)bn * 131072;
  const ushort* Bgh = (const ushort*)Bv + (long)bn * 131072;

  for (int k0 = 0; k0 < 1024; k0 += 64) {
    __syncthreads();
    for (int i = 0; i < 4; ++i) {
      int u = i * 256 + tid;          // unit = 8 bf16; 1024 units per tile
      int row = u >> 3, ch = u & 7;   // 128 rows x 8 chunks
      int goff = row * 1024 + k0 + ch * 8;
      int loff = row * 64 + ch * 8;
      if (a_fp32) {
        float4 s0 = *(const float4*)(Agf + goff);
        float4 s1 = *(const float4*)(Agf + goff + 4);
        uint4 pk = {pack2(s0.x, s0.y), pack2(s0.z, s0.w),
                    pack2(s1.x, s1.y), pack2(s1.z, s1.w)};
        *(uint4*)&As[loff] = pk;
      } else {
        *(uint4*)&As[loff] = *(const uint4*)&Agh[goff];
      }
      if (b_fp32) {
        float4 s0 = *(const float4*)(Bgf + goff);
        float4 s1 = *(const float4*)(Bgf + goff + 4);
        uint4 pk = {pack2(s0.x, s0.y), pack2(s0.z, s0.w),
                    pack2(s1.x, s1.y), pack2(s1.z, s1.w)};
        *(uint4*)&Bs[loff] = pk;
      } else {
        *(uint4*)&Bs[loff] = *(const uint4*)&Bgh[goff];
      }
    }
    __syncthreads();
    for (int kc = 0; kc < 2; ++kc) {
      bf16x8 af[4], bfr[4];
      for (int t = 0; t < 4; ++t)
        af[t] = *(const bf16x8*)&As[(wm + t * 16 + lc) * 64 + kc * 32 + quad * 8];
      for (int t = 0; t < 4; ++t)
        bfr[t] = *(const bf16x8*)&Bs[(wn + t * 16 + lc) * 64 + kc * 32 + quad * 8];
      for (int rt = 0; rt < 4; ++rt)
        for (int ct = 0; ct < 4; ++ct)
          acc[rt][ct] = __builtin_amdgcn_mfma_f32_16x16x32_bf16(
              af[rt], bfr[ct], acc[rt][ct], 0, 0, 0);
    }
  }

  const int row0 = bm * 128 + wm;  // + rt*16 + quad*4 + r
  if (epi == 0) {
    const int e0 = bn * 128;
    const int g = e0 >> 10;                       // 0=q 1=k 2=v (block-uniform)
    const int h = ((e0 & 1023) + wn) >> 6;        // head (wave-uniform)
    const float qs = (g == 0) ? 0.125f * LOG2E : 1.0f;  // fold scale*log2e into q
    ushort* dst = (g == 0) ? qb : ((g == 1) ? kb : vb);
    // rotation freq for pair lc: (1e-4)^(lc/15)
    const float ang = powf(1e-4f, (float)lc * (1.0f / 15.0f));
    for (int rt = 0; rt < 4; ++rt) {
      for (int r = 0; r < 4; ++r) {
        int m = row0 + rt * 16 + quad * 4 + r;
        int srow = m & 2047;
        int b = m >> 11;
        if (g < 2) {  // RoPE: pairs (ct0, ct2); (ct1, ct3) zero-freq identity
          float theta = (float)srow * ang;
          float sn, c;
          sincosf(theta, &sn, &c);
          float x1 = acc[rt][0][r], x2 = acc[rt][2][r];
          acc[rt][0][r] = x1 * c - x2 * sn;
          acc[rt][2][r] = x1 * sn + x2 * c;
        }
        ushort* drow = dst + (((long)b * 16 + h) * 2048 + srow) * 64;
        for (int ct = 0; ct < 4; ++ct)
          drow[ct * 16 + lc] = f2bf(acc[rt][ct][r] * qs);
      }
    }
  } else {
    for (int rt = 0; rt < 4; ++rt)
      for (int r = 0; r < 4; ++r) {
        int m = row0 + rt * 16 + quad * 4 + r;
        float* drow = Cout + (long)m * 1024 + bn * 128 + wn;
        for (int ct = 0; ct < 4; ++ct)
          drow[ct * 16 + lc] = acc[rt][ct][r];
      }
  }
}

// ---------------------------------------------------------------- attention
// One block per (bh, q-tile of 128). 4 waves x 32 q-rows. kv-tiles of 64.
// Scores arrive pre-scaled by 0.125*log2e -> softmax via exp2.
__global__ __launch_bounds__(256) void attn_kernel(
    const ushort* __restrict__ qb, const ushort* __restrict__ kb,
    const ushort* __restrict__ vb, ushort* __restrict__ out) {
  __shared__ __align__(16) ushort Qs[128 * 72];  // [qrow][d], stride 72
  __shared__ __align__(16) ushort Ks[64 * 72];   // [key][d]
  __shared__ __align__(16) ushort Vt[64 * 72];   // [d][key] (transposed)
  __shared__ __align__(16) ushort Ps[128 * 72];  // [qrow][key], wave-private

  const int tid = threadIdx.x, w = tid >> 6, lane = tid & 63;
  const int quad = lane >> 4, lc = lane & 15;
  const int qt = blockIdx.x, bh = blockIdx.y;
  const int bidx = bh >> 4, h = bh & 15;
  const ushort* Q = qb + (long)bh * 2048 * 64 + qt * 128 * 64;
  const ushort* K = kb + (long)bh * 2048 * 64;
  const ushort* V = vb + (long)bh * 2048 * 64;

  for (int i = 0; i < 4; ++i) {  // stage Q tile 128x64
    int u = i * 256 + tid;
    int row = u >> 3, ch = u & 7;
    *(uint4*)&Qs[row * 72 + ch * 8] = *(const uint4*)&Q[row * 64 + ch * 8];
  }

  f32x4 oacc[2][4] = {};
  float mrow[2][4], lrow[2][4];
  for (int rt = 0; rt < 2; ++rt)
    for (int r = 0; r < 4; ++r) { mrow[rt][r] = -3.0e38f; lrow[rt][r] = 0.0f; }

  const int rowbase = qt * 128 + w * 32;  // + rt*16 + quad*4 + r
  const int jmax = 2 * qt + 1;

  for (int j = 0; j <= jmax; ++j) {
    __syncthreads();
    for (int i = 0; i < 2; ++i) {  // stage K (64x64) and V transposed
      int u = i * 256 + tid;
      int row = u >> 3, ch = u & 7;
      *(uint4*)&Ks[row * 72 + ch * 8] = *(const uint4*)&K[(j * 64 + row) * 64 + ch * 8];
      uint4 vv = *(const uint4*)&V[(j * 64 + row) * 64 + ch * 8];
      const ushort* vs = (const ushort*)&vv;
      for (int e = 0; e < 8; ++e) Vt[(ch * 8 + e) * 72 + row] = vs[e];
    }
    __syncthreads();

    f32x4 sacc[2][4] = {};
    for (int kc = 0; kc < 2; ++kc) {  // S = Q K^T over d=64
      bf16x8 qf[2], kf[4];
      for (int rt = 0; rt < 2; ++rt)
        qf[rt] = *(const bf16x8*)&Qs[(w * 32 + rt * 16 + lc) * 72 + kc * 32 + quad * 8];
      for (int ct = 0; ct < 4; ++ct)
        kf[ct] = *(const bf16x8*)&Ks[(ct * 16 + lc) * 72 + kc * 32 + quad * 8];
      for (int rt = 0; rt < 2; ++rt)
        for (int ct = 0; ct < 4; ++ct)
          sacc[rt][ct] = __builtin_amdgcn_mfma_f32_16x16x32_bf16(
              qf[rt], kf[ct], sacc[rt][ct], 0, 0, 0);
    }
    // causal mask
    for (int rt = 0; rt < 2; ++rt)
      for (int ct = 0; ct < 4; ++ct) {
        int key = j * 64 + ct * 16 + lc;
        for (int r = 0; r < 4; ++r) {
          int rowg = rowbase + rt * 16 + quad * 4 + r;
          if (key > rowg) sacc[rt][ct][r] = -1.0e30f;
        }
      }
    for (int rt = 0; rt < 2; ++rt) {  // online softmax (exp2 domain)
      for (int r = 0; r < 4; ++r) {
        float v0 = fmaxf(fmaxf(sacc[rt][0][r], sacc[rt][1][r]),
                         fmaxf(sacc[rt][2][r], sacc[rt][3][r]));
        for (int off = 1; off < 16; off <<= 1) v0 = fmaxf(v0, __shfl_xor(v0, off, 64));
        float mn = fmaxf(mrow[rt][r], v0);
        float alpha = exp2f(mrow[rt][r] - mn);
        mrow[rt][r] = mn;
        float rs = 0.0f;
        for (int ct = 0; ct < 4; ++ct) {
          float p = exp2f(sacc[rt][ct][r] - mn);
          sacc[rt][ct][r] = p;
          rs += p;
        }
        for (int off = 1; off < 16; off <<= 1) rs += __shfl_xor(rs, off, 64);
        lrow[rt][r] = lrow[rt][r] * alpha + rs;
        for (int ct = 0; ct < 4; ++ct) oacc[rt][ct][r] *= alpha;
        for (int ct = 0; ct < 4; ++ct)
          Ps[(w * 32 + rt * 16 + quad * 4 + r) * 72 + ct * 16 + lc] =
              f2bf(sacc[rt][ct][r]);
      }
    }
    // order Ps ushort stores before Ps bf16x8 reads (wave-private rows)
    __threadfence_block();
    // PV
    for (int kc = 0; kc < 2; ++kc) {
      bf16x8 pf[2], vf[4];
      for (int rt = 0; rt < 2; ++rt)
        pf[rt] = *(const bf16x8*)&Ps[(w * 32 + rt * 16 + lc) * 72 + kc * 32 + quad * 8];
      for (int ct = 0; ct < 4; ++ct)
        vf[ct] = *(const bf16x8*)&Vt[(ct * 16 + lc) * 72 + kc * 32 + quad * 8];
      for (int rt = 0; rt < 2; ++rt)
        for (int ct = 0; ct < 4; ++ct)
          oacc[rt][ct] = __builtin_amdgcn_mfma_f32_16x16x32_bf16(
              pf[rt], vf[ct], oacc[rt][ct], 0, 0, 0);
    }
  }

  // epilogue: O/l, store bf16 in [m][h*64+dk] layout (A-ready for out-proj)
  for (int rt = 0; rt < 2; ++rt)
    for (int r = 0; r < 4; ++r) {
      float linv = 1.0f / lrow[rt][r];
      int m = bidx * 2048 + rowbase + rt * 16 + quad * 4 + r;
      ushort* drow = out + (long)m * 1024 + h * 64;
      for (int ct = 0; ct < 4; ++ct)
        drow[ct * 16 + lc] = f2bf(oacc[rt][ct][r] * linv);
    }
}

extern "C" void kernel_launch(void* const* d_in, const int* in_sizes, int n_in,
                              void* d_out, int out_size, void* d_ws, size_t ws_size,
                              hipStream_t stream) {
  const float* x = nullptr;     // 4194304 elems
  const float* Wqkv = nullptr;  // 3145728 elems
  const float* Wo = nullptr;    // 1048576 elems
  for (int i = 0; i < n_in; ++i) {
    if (in_sizes[i] == 4194304) x = (const float*)d_in[i];
    else if (in_sizes[i] == 3145728) Wqkv = (const float*)d_in[i];
    else if (in_sizes[i] == 1048576) Wo = (const float*)d_in[i];
  }
  float* out = (float*)d_out;  // [4096,1024] fp32

  ushort* qbuf = (ushort*)d_ws;          // [B,H,S,64] bf16, 8 MiB
  ushort* kbuf = qbuf + 4194304;         // 8 MiB
  ushort* vbuf = kbuf + 4194304;         // 8 MiB
  ushort* ao   = vbuf + 4194304;         // [m][1024] bf16, 8 MiB

  gemm_bt<<<dim3(32, 24), 256, 0, stream>>>(x, Wqkv, 1, 1, qbuf, kbuf, vbuf,
                                            nullptr, 0);
  attn_kernel<<<dim3(16, 32), 256, 0, stream>>>(qbuf, kbuf, vbuf, ao);
  gemm_bt<<<dim3(32, 8), 256, 0, stream>>>(ao, Wo, 0, 1, nullptr, nullptr,
                                           nullptr, out, 1);
}

// Round 12
// 375.362 us; speedup vs baseline: 37.3033x; 1.1225x over previous
//
#include <hip/hip_runtime.h>
#include <hip/hip_bf16.h>

// B=2, S=2048, D=1024, H=16, dk=64. INPUTS FP32, OUTPUT FP32. M = 4096 rows.
// ROUND 12: barrier-free transposed-score flash attention + pre-transposed V.
// GEMMs unchanged from the passing r11.

typedef __bf16 bf16x8 __attribute__((ext_vector_type(8)));
typedef float f32x4 __attribute__((ext_vector_type(4)));

#define LOG2E 1.4426950408889634f

__device__ __forceinline__ ushort f2bf(float f) {
  __hip_bfloat16 h = __float2bfloat16(f);
  return __builtin_bit_cast(ushort, h);
}

__device__ __forceinline__ uint pack2(float a, float b) {
  return (uint)f2bf(a) | ((uint)f2bf(b) << 16);
}

// ---------------------------------------------------------------- GEMM (NT)
// (unchanged from r11 — validated)
__global__ __launch_bounds__(256) void gemm_bt(
    const void* __restrict__ Av, const void* __restrict__ Bv,
    int a_fp32, int b_fp32,
    ushort* __restrict__ qb, ushort* __restrict__ kb, ushort* __restrict__ vb,
    float* __restrict__ Cout, int epi) {
  __shared__ __align__(16) ushort As[128 * 64];
  __shared__ __align__(16) ushort Bs[128 * 64];
  const int tid = threadIdx.x;
  const int w = tid >> 6, lane = tid & 63, quad = lane >> 4, lc = lane & 15;
  const int bm = blockIdx.x, bn = blockIdx.y;
  const int wm = (w & 1) * 64, wn = (w >> 1) * 64;

  f32x4 acc[4][4] = {};

  const float*  Agf = (const float*)Av + (long)bm * 131072;
  const ushort* Agh = (const ushort*)Av + (long)bm * 131072;
  const float*  Bgf = (const float*)Bv + (long)bn * 131072;
  const ushort* Bgh = (const ushort*)Bv + (long)bn * 131072;

  for (int k0 = 0; k0 < 1024; k0 += 64) {
    __syncthreads();
    for (int i = 0; i < 4; ++i) {
      int u = i * 256 + tid;
      int row = u >> 3, ch = u & 7;
      int goff = row * 1024 + k0 + ch * 8;
      int loff = row * 64 + ch * 8;
      if (a_fp32) {
        float4 s0 = *(const float4*)(Agf + goff);
        float4 s1 = *(const float4*)(Agf + goff + 4);
        uint4 pk = {pack2(s0.x, s0.y), pack2(s0.z, s0.w),
                    pack2(s1.x, s1.y), pack2(s1.z, s1.w)};
        *(uint4*)&As[loff] = pk;
      } else {
        *(uint4*)&As[loff] = *(const uint4*)&Agh[goff];
      }
      if (b_fp32) {
        float4 s0 = *(const float4*)(Bgf + goff);
        float4 s1 = *(const float4*)(Bgf + goff + 4);
        uint4 pk = {pack2(s0.x, s0.y), pack2(s0.z, s0.w),
                    pack2(s1.x, s1.y), pack2(s1.z, s1.w)};
        *(uint4*)&Bs[loff] = pk;
      } else {
        *(uint4*)&Bs[loff] = *(const uint4*)&Bgh[goff];
      }
    }
    __syncthreads();
    for (int kc = 0; kc < 2; ++kc) {
      bf16x8 af[4], bfr[4];
      for (int t = 0; t < 4; ++t)
        af[t] = *(const bf16x8*)&As[(wm + t * 16 + lc) * 64 + kc * 32 + quad * 8];
      for (int t = 0; t < 4; ++t)
        bfr[t] = *(const bf16x8*)&Bs[(wn + t * 16 + lc) * 64 + kc * 32 + quad * 8];
      for (int rt = 0; rt < 4; ++rt)
        for (int ct = 0; ct < 4; ++ct)
          acc[rt][ct] = __builtin_amdgcn_mfma_f32_16x16x32_bf16(
              af[rt], bfr[ct], acc[rt][ct], 0, 0, 0);
    }
  }

  const int row0 = bm * 128 + wm;
  if (epi == 0) {
    const int e0 = bn * 128;
    const int g = e0 >> 10;
    const int h = ((e0 & 1023) + wn) >> 6;
    const float qs = (g == 0) ? 0.125f * LOG2E : 1.0f;
    ushort* dst = (g == 0) ? qb : ((g == 1) ? kb : vb);
    const float ang = powf(1e-4f, (float)lc * (1.0f / 15.0f));
    for (int rt = 0; rt < 4; ++rt) {
      for (int r = 0; r < 4; ++r) {
        int m = row0 + rt * 16 + quad * 4 + r;
        int srow = m & 2047;
        int b = m >> 11;
        if (g < 2) {
          float theta = (float)srow * ang;
          float sn, c;
          sincosf(theta, &sn, &c);
          float x1 = acc[rt][0][r], x2 = acc[rt][2][r];
          acc[rt][0][r] = x1 * c - x2 * sn;
          acc[rt][2][r] = x1 * sn + x2 * c;
        }
        ushort* drow = dst + (((long)b * 16 + h) * 2048 + srow) * 64;
        for (int ct = 0; ct < 4; ++ct)
          drow[ct * 16 + lc] = f2bf(acc[rt][ct][r] * qs);
      }
    }
  } else {
    for (int rt = 0; rt < 4; ++rt)
      for (int r = 0; r < 4; ++r) {
        int m = row0 + rt * 16 + quad * 4 + r;
        float* drow = Cout + (long)m * 1024 + bn * 128 + wn;
        for (int ct = 0; ct < 4; ++ct)
          drow[ct * 16 + lc] = acc[rt][ct][r];
      }
  }
}

// ----------------------------------------------------------- V transpose
// vb [bh][s][64] -> vt [bh][64][2048]. One block per (s-chunk 64, bh).
__global__ __launch_bounds__(256) void vtrans(const ushort* __restrict__ vb,
                                              ushort* __restrict__ vt) {
  __shared__ __align__(16) ushort T[64 * 72];
  const int tid = threadIdx.x, sc = blockIdx.x, bh = blockIdx.y;
  const ushort* src = vb + ((long)bh * 2048 + sc * 64) * 64;
  for (int i = 0; i < 2; ++i) {
    int u = i * 256 + tid;         // 0..511
    int row = u >> 3, ch = u & 7;  // s-row 0..63, d-chunk 0..7
    uint4 vv = *(const uint4*)&src[row * 64 + ch * 8];
    const ushort* e = (const ushort*)&vv;
    for (int t = 0; t < 8; ++t) T[(ch * 8 + t) * 72 + row] = e[t];
  }
  __syncthreads();
  for (int i = 0; i < 2; ++i) {
    int u = i * 256 + tid;
    int d = u >> 3, ch = u & 7;    // d 0..63, s-chunk 0..7
    uint4 vv = *(const uint4*)&T[d * 72 + ch * 8];
    *(uint4*)&vt[((long)bh * 64 + d) * 2048 + sc * 64 + ch * 8] = vv;
  }
}

// ---------------------------------------------------------------- attention
// Barrier-free. Block = 4 independent waves; wave handles 32 q-rows.
// Scores computed TRANSPOSED (S^T = K·Q^T) so softmax is in-register.
// P round-trips through per-wave XOR-swizzled LDS (no __syncthreads).
// q pre-scaled by 0.125*log2e -> exp2 softmax.
__global__ __launch_bounds__(256) void attn_kernel(
    const ushort* __restrict__ qb, const ushort* __restrict__ kb,
    const ushort* __restrict__ vt, ushort* __restrict__ out) {
  __shared__ __align__(16) ushort Ps[4 * 32 * 64];  // per-wave 32x64 swizzled
  const int tid = threadIdx.x, w = tid >> 6, lane = tid & 63;
  const int quad = lane >> 4, lc = lane & 15, l7 = lc & 7;
  const int qt = 15 - blockIdx.x;  // big tiles first
  const int bh = blockIdx.y;
  const int bidx = bh >> 4, h = bh & 15;
  const int qtbase = qt * 128 + w * 32;
  ushort* Psw = &Ps[w * 32 * 64];

  // Q fragments held in registers for the whole kernel: qf[kc][q2]
  bf16x8 qf[2][2];
  for (int kc = 0; kc < 2; ++kc)
    for (int q2 = 0; q2 < 2; ++q2)
      qf[kc][q2] = *(const bf16x8*)&qb[((long)bh * 2048 + qtbase + q2 * 16 + lc) * 64 +
                                       kc * 32 + quad * 8];

  f32x4 oacc[4][2] = {};  // O^T: [d-tile][q-tile]
  float m_[2] = {-3.0e38f, -3.0e38f}, l_[2] = {0.0f, 0.0f};

  const ushort* K = kb + (long)bh * 2048 * 64;
  const ushort* Vt = vt + (long)bh * 64 * 2048;
  const int jmax = 2 * qt + (w >> 1);
  const int rowoff = (w & 1) * 32;

  for (int j = 0; j <= jmax; ++j) {
    // S^T = K·Q^T (A=K rows=keys, B=Q rows=queries; both k=d contiguous)
    f32x4 sacc[4][2] = {};
    for (int kc = 0; kc < 2; ++kc) {
      bf16x8 kf[4];
      for (int kt = 0; kt < 4; ++kt)
        kf[kt] = *(const bf16x8*)&K[(long)(j * 64 + kt * 16 + lc) * 64 +
                                    kc * 32 + quad * 8];
      for (int kt = 0; kt < 4; ++kt)
        for (int q2 = 0; q2 < 2; ++q2)
          sacc[kt][q2] = __builtin_amdgcn_mfma_f32_16x16x32_bf16(
              kf[kt], qf[kc][q2], sacc[kt][q2], 0, 0, 0);
    }
    if (j == jmax) {  // only the last tile is causal-partial (wave-uniform)
      for (int kt = 0; kt < 4; ++kt)
        for (int q2 = 0; q2 < 2; ++q2) {
          int rowrel = rowoff + q2 * 16 + lc;
          for (int r = 0; r < 4; ++r)
            if (kt * 16 + quad * 4 + r > rowrel) sacc[kt][q2][r] = -1.0e30f;
        }
    }
    // online softmax: lane holds 16 keys per q-column -> in-register + 2 shfl
    for (int q2 = 0; q2 < 2; ++q2) {
      float vm = sacc[0][q2][0];
      for (int kt = 0; kt < 4; ++kt)
        for (int r = 0; r < 4; ++r) vm = fmaxf(vm, sacc[kt][q2][r]);
      vm = fmaxf(vm, __shfl_xor(vm, 16, 64));
      vm = fmaxf(vm, __shfl_xor(vm, 32, 64));
      float mn = fmaxf(m_[q2], vm);
      float alpha = exp2f(m_[q2] - mn);
      m_[q2] = mn;
      float rs = 0.0f;
      float p[4][4];
      for (int kt = 0; kt < 4; ++kt)
        for (int r = 0; r < 4; ++r) {
          p[kt][r] = exp2f(sacc[kt][q2][r] - mn);
          rs += p[kt][r];
        }
      rs += __shfl_xor(rs, 16, 64);
      rs += __shfl_xor(rs, 32, 64);
      l_[q2] = l_[q2] * alpha + rs;
      for (int mt = 0; mt < 4; ++mt) oacc[mt][q2] *= alpha;
      // store P[q][key] with XOR-swizzled 8-key chunks (b64 per kt)
      for (int kt = 0; kt < 4; ++kt) {
        uint2 pk = {pack2(p[kt][0], p[kt][1]), pack2(p[kt][2], p[kt][3])};
        *(uint2*)&Psw[(q2 * 16 + lc) * 64 + (((kt * 2 + (quad >> 1)) ^ l7) << 3) +
                      ((quad & 1) << 2)] = pk;
      }
    }
    __threadfence_block();  // order Ps writes before swizzled reads
    // O^T += Vt·P^T  (A=Vt rows=d, B=P rows=q; both k=key contiguous)
    for (int kc = 0; kc < 2; ++kc) {
      bf16x8 vf[4], pf[2];
      for (int mt = 0; mt < 4; ++mt)
        vf[mt] = *(const bf16x8*)&Vt[(long)(mt * 16 + lc) * 2048 + j * 64 +
                                     kc * 32 + quad * 8];
      for (int q2 = 0; q2 < 2; ++q2)
        pf[q2] = *(const bf16x8*)&Psw[(q2 * 16 + lc) * 64 +
                                      (((kc * 4 + quad) ^ l7) << 3)];
      for (int mt = 0; mt < 4; ++mt)
        for (int q2 = 0; q2 < 2; ++q2)
          oacc[mt][q2] = __builtin_amdgcn_mfma_f32_16x16x32_bf16(
              vf[mt], pf[q2], oacc[mt][q2], 0, 0, 0);
    }
    __threadfence_block();  // order Ps reads before next iter's overwrites
  }

  // epilogue: O^T/l -> LDS (same swizzle) -> coalesced bf16 rows of ao
  for (int q2 = 0; q2 < 2; ++q2) {
    float linv = 1.0f / l_[q2];
    for (int mt = 0; mt < 4; ++mt) {
      uint2 pk = {pack2(oacc[mt][q2][0] * linv, oacc[mt][q2][1] * linv),
                  pack2(oacc[mt][q2][2] * linv, oacc[mt][q2][3] * linv)};
      *(uint2*)&Psw[(q2 * 16 + lc) * 64 + (((mt * 2 + (quad >> 1)) ^ l7) << 3) +
                    ((quad & 1) << 2)] = pk;
    }
  }
  __threadfence_block();
  {
    int r2 = lane >> 1;  // 0..31 local q-row
    long mrow = (long)bidx * 2048 + qtbase + r2;
    for (int c = 0; c < 4; ++c) {
      int c8 = (lane & 1) * 4 + c;  // d-chunk 0..7
      uint4 vv = *(const uint4*)&Psw[r2 * 64 + ((c8 ^ (r2 & 7)) << 3)];
      *(uint4*)&out[mrow * 1024 + h * 64 + c8 * 8] = vv;
    }
  }
}

extern "C" void kernel_launch(void* const* d_in, const int* in_sizes, int n_in,
                              void* d_out, int out_size, void* d_ws, size_t ws_size,
                              hipStream_t stream) {
  const float* x = nullptr;     // 4194304 elems
  const float* Wqkv = nullptr;  // 3145728 elems
  const float* Wo = nullptr;    // 1048576 elems
  for (int i = 0; i < n_in; ++i) {
    if (in_sizes[i] == 4194304) x = (const float*)d_in[i];
    else if (in_sizes[i] == 3145728) Wqkv = (const float*)d_in[i];
    else if (in_sizes[i] == 1048576) Wo = (const float*)d_in[i];
  }
  float* out = (float*)d_out;  // [4096,1024] fp32

  // 32 MiB workspace layout (ws >= 32 MiB proven in r5):
  ushort* qbuf = (ushort*)d_ws;          // [bh][s][64]   0..8 MiB
  ushort* kbuf = qbuf + 4194304;         //               8..16 MiB
  ushort* vbuf = kbuf + 4194304;         //              16..24 MiB
  ushort* vtb  = vbuf + 4194304;         // [bh][64][s]  24..32 MiB
  ushort* ao   = vbuf;                   // aliases vbuf (dead after vtrans)

  gemm_bt<<<dim3(32, 24), 256, 0, stream>>>(x, Wqkv, 1, 1, qbuf, kbuf, vbuf,
                                            nullptr, 0);
  vtrans<<<dim3(32, 32), 256, 0, stream>>>(vbuf, vtb);
  attn_kernel<<<dim3(16, 32), 256, 0, stream>>>(qbuf, kbuf, vtb, ao);
  gemm_bt<<<dim3(32, 8), 256, 0, stream>>>(ao, Wo, 0, 1, nullptr, nullptr,
                                           nullptr, out, 1);
}

// Round 13
// 290.550 us; speedup vs baseline: 48.1923x; 1.2919x over previous
//
#include <hip/hip_runtime.h>
#include <hip/hip_bf16.h>

// B=2, S=2048, D=1024, H=16, dk=64. INPUTS FP32, OUTPUT FP32. M = 4096 rows.
// ROUND 13: bf16 pre-conversion + global_load_lds(width=16) staging for both
// GEMM operands (m97 structure). d_out doubles as x_bf16 scratch (oproj
// rewrites it at the end). Attention/vtrans unchanged from r12.

typedef __bf16 bf16x8 __attribute__((ext_vector_type(8)));
typedef float f32x4 __attribute__((ext_vector_type(4)));

#define LOG2E 1.4426950408889634f

__device__ __forceinline__ ushort f2bf(float f) {
  __hip_bfloat16 h = __float2bfloat16(f);
  return __builtin_bit_cast(ushort, h);
}

__device__ __forceinline__ uint pack2(float a, float b) {
  return (uint)f2bf(a) | ((uint)f2bf(b) << 16);
}

__device__ __forceinline__ void gl2lds16(const ushort* g, ushort* l) {
  __builtin_amdgcn_global_load_lds(
      (const __attribute__((address_space(1))) void*)g,
      (__attribute__((address_space(3))) void*)l, 16, 0, 0);
}

// ------------------------------------------------------------ fp32 -> bf16
__global__ __launch_bounds__(256) void conv_bf16(const float* __restrict__ src,
                                                 ushort* __restrict__ dst,
                                                 int n8) {
  int i = blockIdx.x * 256 + threadIdx.x;
  if (i >= n8) return;
  const float4* s = (const float4*)src + (long)i * 2;
  float4 a = s[0], b = s[1];
  uint4 pk = {pack2(a.x, a.y), pack2(a.z, a.w), pack2(b.x, b.y), pack2(b.z, b.w)};
  ((uint4*)dst)[i] = pk;
}

// ---------------------------------------------------------------- GEMM (NT)
// C[m][n] = sum_k A[m][k]*B[n][k], K=1024, both operands bf16 [rows][1024].
// 128x128 tile, 4 waves of 64x64. Staging via global_load_lds width=16
// (wave-uniform LDS base + lane*16 — LDS layout matches unit order exactly).
// 1D grid, bn-fastest: bm = bid/nbn, bn = bid%nbn (per-XCD B-column reuse).
// epi==0: QKV epilogue (inline RoPE + q-scale + scatter to q/k/v [B,H,S,64])
// epi==1: fp32 store to Cout [m][n]
__global__ __launch_bounds__(256) void gemm_bt(
    const ushort* __restrict__ A, const ushort* __restrict__ B, int nbn,
    ushort* __restrict__ qb, ushort* __restrict__ kb, ushort* __restrict__ vb,
    float* __restrict__ Cout, int epi) {
  __shared__ __align__(16) ushort As[128 * 64];
  __shared__ __align__(16) ushort Bs[128 * 64];
  const int tid = threadIdx.x;
  const int w = tid >> 6, lane = tid & 63, quad = lane >> 4, lc = lane & 15;
  const int bid = blockIdx.x;
  const int bm = bid / nbn, bn = bid % nbn;
  const int wm = (w & 1) * 64, wn = (w >> 1) * 64;

  f32x4 acc[4][4] = {};

  const ushort* Ag = A + (long)bm * 131072;
  const ushort* Bg = B + (long)bn * 131072;

  for (int k0 = 0; k0 < 1024; k0 += 64) {
    __syncthreads();
    for (int i = 0; i < 4; ++i) {
      int u = i * 256 + tid;          // unit = 8 bf16 = 16 B; 1024 units/tile
      int row = u >> 3, ch = u & 7;   // 128 rows x 8 chunks
      gl2lds16(Ag + row * 1024 + k0 + ch * 8, &As[(i * 256 + w * 64) * 8]);
      gl2lds16(Bg + row * 1024 + k0 + ch * 8, &Bs[(i * 256 + w * 64) * 8]);
    }
    __builtin_amdgcn_s_waitcnt(0);  // drain DMAs
    __syncthreads();
    for (int kc = 0; kc < 2; ++kc) {
      bf16x8 af[4], bfr[4];
      for (int t = 0; t < 4; ++t)
        af[t] = *(const bf16x8*)&As[(wm + t * 16 + lc) * 64 + kc * 32 + quad * 8];
      for (int t = 0; t < 4; ++t)
        bfr[t] = *(const bf16x8*)&Bs[(wn + t * 16 + lc) * 64 + kc * 32 + quad * 8];
      for (int rt = 0; rt < 4; ++rt)
        for (int ct = 0; ct < 4; ++ct)
          acc[rt][ct] = __builtin_amdgcn_mfma_f32_16x16x32_bf16(
              af[rt], bfr[ct], acc[rt][ct], 0, 0, 0);
    }
  }

  const int row0 = bm * 128 + wm;  // + rt*16 + quad*4 + r
  if (epi == 0) {
    const int e0 = bn * 128;
    const int g = e0 >> 10;                       // 0=q 1=k 2=v (block-uniform)
    const int h = ((e0 & 1023) + wn) >> 6;        // head (wave-uniform)
    const float qs = (g == 0) ? 0.125f * LOG2E : 1.0f;  // fold scale*log2e into q
    ushort* dst = (g == 0) ? qb : ((g == 1) ? kb : vb);
    const float ang = powf(1e-4f, (float)lc * (1.0f / 15.0f));
    for (int rt = 0; rt < 4; ++rt) {
      for (int r = 0; r < 4; ++r) {
        int m = row0 + rt * 16 + quad * 4 + r;
        int srow = m & 2047;
        int b = m >> 11;
        if (g < 2) {  // RoPE: pairs (ct0, ct2); (ct1, ct3) zero-freq identity
          float theta = (float)srow * ang;
          float sn, c;
          sincosf(theta, &sn, &c);
          float x1 = acc[rt][0][r], x2 = acc[rt][2][r];
          acc[rt][0][r] = x1 * c - x2 * sn;
          acc[rt][2][r] = x1 * sn + x2 * c;
        }
        ushort* drow = dst + (((long)b * 16 + h) * 2048 + srow) * 64;
        for (int ct = 0; ct < 4; ++ct)
          drow[ct * 16 + lc] = f2bf(acc[rt][ct][r] * qs);
      }
    }
  } else {
    for (int rt = 0; rt < 4; ++rt)
      for (int r = 0; r < 4; ++r) {
        int m = row0 + rt * 16 + quad * 4 + r;
        float* drow = Cout + (long)m * 1024 + bn * 128 + wn;
        for (int ct = 0; ct < 4; ++ct)
          drow[ct * 16 + lc] = acc[rt][ct][r];
      }
  }
}

// ----------------------------------------------------------- V transpose
// vb [bh][s][64] -> vt [bh][64][2048]. One block per (s-chunk 64, bh).
__global__ __launch_bounds__(256) void vtrans(const ushort* __restrict__ vb,
                                              ushort* __restrict__ vt) {
  __shared__ __align__(16) ushort T[64 * 72];
  const int tid = threadIdx.x, sc = blockIdx.x, bh = blockIdx.y;
  const ushort* src = vb + ((long)bh * 2048 + sc * 64) * 64;
  for (int i = 0; i < 2; ++i) {
    int u = i * 256 + tid;
    int row = u >> 3, ch = u & 7;
    uint4 vv = *(const uint4*)&src[row * 64 + ch * 8];
    const ushort* e = (const ushort*)&vv;
    for (int t = 0; t < 8; ++t) T[(ch * 8 + t) * 72 + row] = e[t];
  }
  __syncthreads();
  for (int i = 0; i < 2; ++i) {
    int u = i * 256 + tid;
    int d = u >> 3, ch = u & 7;
    uint4 vv = *(const uint4*)&T[d * 72 + ch * 8];
    *(uint4*)&vt[((long)bh * 64 + d) * 2048 + sc * 64 + ch * 8] = vv;
  }
}

// ---------------------------------------------------------------- attention
// (unchanged from r12 — barrier-free transposed-score flash attention)
__global__ __launch_bounds__(256) void attn_kernel(
    const ushort* __restrict__ qb, const ushort* __restrict__ kb,
    const ushort* __restrict__ vt, ushort* __restrict__ out) {
  __shared__ __align__(16) ushort Ps[4 * 32 * 64];
  const int tid = threadIdx.x, w = tid >> 6, lane = tid & 63;
  const int quad = lane >> 4, lc = lane & 15, l7 = lc & 7;
  const int qt = 15 - blockIdx.x;
  const int bh = blockIdx.y;
  const int bidx = bh >> 4, h = bh & 15;
  const int qtbase = qt * 128 + w * 32;
  ushort* Psw = &Ps[w * 32 * 64];

  bf16x8 qf[2][2];
  for (int kc = 0; kc < 2; ++kc)
    for (int q2 = 0; q2 < 2; ++q2)
      qf[kc][q2] = *(const bf16x8*)&qb[((long)bh * 2048 + qtbase + q2 * 16 + lc) * 64 +
                                       kc * 32 + quad * 8];

  f32x4 oacc[4][2] = {};
  float m_[2] = {-3.0e38f, -3.0e38f}, l_[2] = {0.0f, 0.0f};

  const ushort* K = kb + (long)bh * 2048 * 64;
  const ushort* Vt = vt + (long)bh * 64 * 2048;
  const int jmax = 2 * qt + (w >> 1);
  const int rowoff = (w & 1) * 32;

  for (int j = 0; j <= jmax; ++j) {
    f32x4 sacc[4][2] = {};
    for (int kc = 0; kc < 2; ++kc) {
      bf16x8 kf[4];
      for (int kt = 0; kt < 4; ++kt)
        kf[kt] = *(const bf16x8*)&K[(long)(j * 64 + kt * 16 + lc) * 64 +
                                    kc * 32 + quad * 8];
      for (int kt = 0; kt < 4; ++kt)
        for (int q2 = 0; q2 < 2; ++q2)
          sacc[kt][q2] = __builtin_amdgcn_mfma_f32_16x16x32_bf16(
              kf[kt], qf[kc][q2], sacc[kt][q2], 0, 0, 0);
    }
    if (j == jmax) {
      for (int kt = 0; kt < 4; ++kt)
        for (int q2 = 0; q2 < 2; ++q2) {
          int rowrel = rowoff + q2 * 16 + lc;
          for (int r = 0; r < 4; ++r)
            if (kt * 16 + quad * 4 + r > rowrel) sacc[kt][q2][r] = -1.0e30f;
        }
    }
    for (int q2 = 0; q2 < 2; ++q2) {
      float vm = sacc[0][q2][0];
      for (int kt = 0; kt < 4; ++kt)
        for (int r = 0; r < 4; ++r) vm = fmaxf(vm, sacc[kt][q2][r]);
      vm = fmaxf(vm, __shfl_xor(vm, 16, 64));
      vm = fmaxf(vm, __shfl_xor(vm, 32, 64));
      float mn = fmaxf(m_[q2], vm);
      float alpha = exp2f(m_[q2] - mn);
      m_[q2] = mn;
      float rs = 0.0f;
      float p[4][4];
      for (int kt = 0; kt < 4; ++kt)
        for (int r = 0; r < 4; ++r) {
          p[kt][r] = exp2f(sacc[kt][q2][r] - mn);
          rs += p[kt][r];
        }
      rs += __shfl_xor(rs, 16, 64);
      rs += __shfl_xor(rs, 32, 64);
      l_[q2] = l_[q2] * alpha + rs;
      for (int mt = 0; mt < 4; ++mt) oacc[mt][q2] *= alpha;
      for (int kt = 0; kt < 4; ++kt) {
        uint2 pk = {pack2(p[kt][0], p[kt][1]), pack2(p[kt][2], p[kt][3])};
        *(uint2*)&Psw[(q2 * 16 + lc) * 64 + (((kt * 2 + (quad >> 1)) ^ l7) << 3) +
                      ((quad & 1) << 2)] = pk;
      }
    }
    __threadfence_block();
    for (int kc = 0; kc < 2; ++kc) {
      bf16x8 vf[4], pf[2];
      for (int mt = 0; mt < 4; ++mt)
        vf[mt] = *(const bf16x8*)&Vt[(long)(mt * 16 + lc) * 2048 + j * 64 +
                                     kc * 32 + quad * 8];
      for (int q2 = 0; q2 < 2; ++q2)
        pf[q2] = *(const bf16x8*)&Psw[(q2 * 16 + lc) * 64 +
                                      (((kc * 4 + quad) ^ l7) << 3)];
      for (int mt = 0; mt < 4; ++mt)
        for (int q2 = 0; q2 < 2; ++q2)
          oacc[mt][q2] = __builtin_amdgcn_mfma_f32_16x16x32_bf16(
              vf[mt], pf[q2], oacc[mt][q2], 0, 0, 0);
    }
    __threadfence_block();
  }

  for (int q2 = 0; q2 < 2; ++q2) {
    float linv = 1.0f / l_[q2];
    for (int mt = 0; mt < 4; ++mt) {
      uint2 pk = {pack2(oacc[mt][q2][0] * linv, oacc[mt][q2][1] * linv),
                  pack2(oacc[mt][q2][2] * linv, oacc[mt][q2][3] * linv)};
      *(uint2*)&Psw[(q2 * 16 + lc) * 64 + (((mt * 2 + (quad >> 1)) ^ l7) << 3) +
                    ((quad & 1) << 2)] = pk;
    }
  }
  __threadfence_block();
  {
    int r2 = lane >> 1;
    long mrow = (long)bidx * 2048 + qtbase + r2;
    for (int c = 0; c < 4; ++c) {
      int c8 = (lane & 1) * 4 + c;
      uint4 vv = *(const uint4*)&Psw[r2 * 64 + ((c8 ^ (r2 & 7)) << 3)];
      *(uint4*)&out[mrow * 1024 + h * 64 + c8 * 8] = vv;
    }
  }
}

extern "C" void kernel_launch(void* const* d_in, const int* in_sizes, int n_in,
                              void* d_out, int out_size, void* d_ws, size_t ws_size,
                              hipStream_t stream) {
  const float* x = nullptr;     // 4194304 elems
  const float* Wqkv = nullptr;  // 3145728 elems
  const float* Wo = nullptr;    // 1048576 elems
  for (int i = 0; i < n_in; ++i) {
    if (in_sizes[i] == 4194304) x = (const float*)d_in[i];
    else if (in_sizes[i] == 3145728) Wqkv = (const float*)d_in[i];
    else if (in_sizes[i] == 1048576) Wo = (const float*)d_in[i];
  }
  float* out = (float*)d_out;  // [4096,1024] fp32 (16 MiB)

  // Workspace (32 MiB) + d_out-as-scratch timeline:
  //  d_out[0..8M):  x_bf16 (conv) -> consumed by QKV GEMM -> overwritten by oproj
  //  ws [0..8):  q            | after attn: [0..2) Wo_bf16 (conv)
  //  ws [8..16): k
  //  ws [16..24): v -> ao (attn output; v dead after vtrans)
  //  ws [24..30): Wqkv_bf16 -> clobbered by vt after QKV GEMM
  //  ws [24..32): vt (V transposed)
  ushort* qbuf = (ushort*)d_ws;
  ushort* kbuf = qbuf + 4194304;
  ushort* vbuf = kbuf + 4194304;
  ushort* vtb  = vbuf + 4194304;
  ushort* wqkvh = vtb;                 // [24..30) before vtrans
  ushort* woh  = qbuf;                 // [0..2) after attn
  ushort* ao   = vbuf;                 // aliases vbuf
  ushort* xh   = (ushort*)d_out;       // x_bf16 in d_out scratch

  conv_bf16<<<2048, 256, 0, stream>>>(x, xh, 524288);
  conv_bf16<<<1536, 256, 0, stream>>>(Wqkv, wqkvh, 393216);
  gemm_bt<<<768, 256, 0, stream>>>(xh, wqkvh, 24, qbuf, kbuf, vbuf, nullptr, 0);
  vtrans<<<dim3(32, 32), 256, 0, stream>>>(vbuf, vtb);
  attn_kernel<<<dim3(16, 32), 256, 0, stream>>>(qbuf, kbuf, vtb, ao);
  conv_bf16<<<512, 256, 0, stream>>>(Wo, woh, 131072);
  gemm_bt<<<256, 256, 0, stream>>>(ao, woh, 8, nullptr, nullptr, nullptr, out, 1);
}

// Round 14
// 256.329 us; speedup vs baseline: 54.6261x; 1.1335x over previous
//
#include <hip/hip_runtime.h>
#include <hip/hip_bf16.h>

// B=2, S=2048, D=1024, H=16, dk=64. INPUTS FP32, OUTPUT FP32. M = 4096 rows.
// ROUND 14: wave-granular attention (1 wave = 1 block = 32 q-rows), grid 2048
// blocks in descending-work order. Per-wave math identical to r12/r13.
// GEMMs/convs/vtrans unchanged from r13.

typedef __bf16 bf16x8 __attribute__((ext_vector_type(8)));
typedef float f32x4 __attribute__((ext_vector_type(4)));

#define LOG2E 1.4426950408889634f

__device__ __forceinline__ ushort f2bf(float f) {
  __hip_bfloat16 h = __float2bfloat16(f);
  return __builtin_bit_cast(ushort, h);
}

__device__ __forceinline__ uint pack2(float a, float b) {
  return (uint)f2bf(a) | ((uint)f2bf(b) << 16);
}

__device__ __forceinline__ void gl2lds16(const ushort* g, ushort* l) {
  __builtin_amdgcn_global_load_lds(
      (const __attribute__((address_space(1))) void*)g,
      (__attribute__((address_space(3))) void*)l, 16, 0, 0);
}

// ------------------------------------------------------------ fp32 -> bf16
__global__ __launch_bounds__(256) void conv_bf16(const float* __restrict__ src,
                                                 ushort* __restrict__ dst,
                                                 int n8) {
  int i = blockIdx.x * 256 + threadIdx.x;
  if (i >= n8) return;
  const float4* s = (const float4*)src + (long)i * 2;
  float4 a = s[0], b = s[1];
  uint4 pk = {pack2(a.x, a.y), pack2(a.z, a.w), pack2(b.x, b.y), pack2(b.z, b.w)};
  ((uint4*)dst)[i] = pk;
}

// ---------------------------------------------------------------- GEMM (NT)
// (unchanged from r13 — validated)
__global__ __launch_bounds__(256) void gemm_bt(
    const ushort* __restrict__ A, const ushort* __restrict__ B, int nbn,
    ushort* __restrict__ qb, ushort* __restrict__ kb, ushort* __restrict__ vb,
    float* __restrict__ Cout, int epi) {
  __shared__ __align__(16) ushort As[128 * 64];
  __shared__ __align__(16) ushort Bs[128 * 64];
  const int tid = threadIdx.x;
  const int w = tid >> 6, lane = tid & 63, quad = lane >> 4, lc = lane & 15;
  const int bid = blockIdx.x;
  const int bm = bid / nbn, bn = bid % nbn;
  const int wm = (w & 1) * 64, wn = (w >> 1) * 64;

  f32x4 acc[4][4] = {};

  const ushort* Ag = A + (long)bm * 131072;
  const ushort* Bg = B + (long)bn * 131072;

  for (int k0 = 0; k0 < 1024; k0 += 64) {
    __syncthreads();
    for (int i = 0; i < 4; ++i) {
      int u = i * 256 + tid;
      int row = u >> 3, ch = u & 7;
      gl2lds16(Ag + row * 1024 + k0 + ch * 8, &As[(i * 256 + w * 64) * 8]);
      gl2lds16(Bg + row * 1024 + k0 + ch * 8, &Bs[(i * 256 + w * 64) * 8]);
    }
    __builtin_amdgcn_s_waitcnt(0);
    __syncthreads();
    for (int kc = 0; kc < 2; ++kc) {
      bf16x8 af[4], bfr[4];
      for (int t = 0; t < 4; ++t)
        af[t] = *(const bf16x8*)&As[(wm + t * 16 + lc) * 64 + kc * 32 + quad * 8];
      for (int t = 0; t < 4; ++t)
        bfr[t] = *(const bf16x8*)&Bs[(wn + t * 16 + lc) * 64 + kc * 32 + quad * 8];
      for (int rt = 0; rt < 4; ++rt)
        for (int ct = 0; ct < 4; ++ct)
          acc[rt][ct] = __builtin_amdgcn_mfma_f32_16x16x32_bf16(
              af[rt], bfr[ct], acc[rt][ct], 0, 0, 0);
    }
  }

  const int row0 = bm * 128 + wm;
  if (epi == 0) {
    const int e0 = bn * 128;
    const int g = e0 >> 10;
    const int h = ((e0 & 1023) + wn) >> 6;
    const float qs = (g == 0) ? 0.125f * LOG2E : 1.0f;
    ushort* dst = (g == 0) ? qb : ((g == 1) ? kb : vb);
    const float ang = powf(1e-4f, (float)lc * (1.0f / 15.0f));
    for (int rt = 0; rt < 4; ++rt) {
      for (int r = 0; r < 4; ++r) {
        int m = row0 + rt * 16 + quad * 4 + r;
        int srow = m & 2047;
        int b = m >> 11;
        if (g < 2) {
          float theta = (float)srow * ang;
          float sn, c;
          sincosf(theta, &sn, &c);
          float x1 = acc[rt][0][r], x2 = acc[rt][2][r];
          acc[rt][0][r] = x1 * c - x2 * sn;
          acc[rt][2][r] = x1 * sn + x2 * c;
        }
        ushort* drow = dst + (((long)b * 16 + h) * 2048 + srow) * 64;
        for (int ct = 0; ct < 4; ++ct)
          drow[ct * 16 + lc] = f2bf(acc[rt][ct][r] * qs);
      }
    }
  } else {
    for (int rt = 0; rt < 4; ++rt)
      for (int r = 0; r < 4; ++r) {
        int m = row0 + rt * 16 + quad * 4 + r;
        float* drow = Cout + (long)m * 1024 + bn * 128 + wn;
        for (int ct = 0; ct < 4; ++ct)
          drow[ct * 16 + lc] = acc[rt][ct][r];
      }
  }
}

// ----------------------------------------------------------- V transpose
__global__ __launch_bounds__(256) void vtrans(const ushort* __restrict__ vb,
                                              ushort* __restrict__ vt) {
  __shared__ __align__(16) ushort T[64 * 72];
  const int tid = threadIdx.x, sc = blockIdx.x, bh = blockIdx.y;
  const ushort* src = vb + ((long)bh * 2048 + sc * 64) * 64;
  for (int i = 0; i < 2; ++i) {
    int u = i * 256 + tid;
    int row = u >> 3, ch = u & 7;
    uint4 vv = *(const uint4*)&src[row * 64 + ch * 8];
    const ushort* e = (const ushort*)&vv;
    for (int t = 0; t < 8; ++t) T[(ch * 8 + t) * 72 + row] = e[t];
  }
  __syncthreads();
  for (int i = 0; i < 2; ++i) {
    int u = i * 256 + tid;
    int d = u >> 3, ch = u & 7;
    uint4 vv = *(const uint4*)&T[d * 72 + ch * 8];
    *(uint4*)&vt[((long)bh * 64 + d) * 2048 + sc * 64 + ch * 8] = vv;
  }
}

// ---------------------------------------------------------------- attention
// ONE WAVE PER BLOCK. strip s = 32 q-rows; jmax = s>>1; rowoff = 32*(s&1).
// Scores transposed (S^T = K·Q^T), softmax in-register, P via swizzled LDS.
__global__ __launch_bounds__(64) void attn_kernel(
    const ushort* __restrict__ qb, const ushort* __restrict__ kb,
    const ushort* __restrict__ vt, ushort* __restrict__ out) {
  __shared__ __align__(16) ushort Psw[32 * 64];  // 4 KB, wave-private
  const int lane = threadIdx.x;
  const int quad = lane >> 4, lc = lane & 15, l7 = lc & 7;
  const int bid = blockIdx.x;                   // 0..2047
  const int s = 63 - (bid >> 5);                // strip, big-work first
  const int bh = bid & 31;
  const int bidx = bh >> 4, h = bh & 15;
  const int qtbase = s * 32;

  bf16x8 qf[2][2];
  for (int kc = 0; kc < 2; ++kc)
    for (int q2 = 0; q2 < 2; ++q2)
      qf[kc][q2] = *(const bf16x8*)&qb[((long)bh * 2048 + qtbase + q2 * 16 + lc) * 64 +
                                       kc * 32 + quad * 8];

  f32x4 oacc[4][2] = {};
  float m_[2] = {-3.0e38f, -3.0e38f}, l_[2] = {0.0f, 0.0f};

  const ushort* K = kb + (long)bh * 2048 * 64;
  const ushort* Vt = vt + (long)bh * 64 * 2048;
  const int jmax = s >> 1;
  const int rowoff = (s & 1) * 32;

  for (int j = 0; j <= jmax; ++j) {
    f32x4 sacc[4][2] = {};
    for (int kc = 0; kc < 2; ++kc) {
      bf16x8 kf[4];
      for (int kt = 0; kt < 4; ++kt)
        kf[kt] = *(const bf16x8*)&K[(long)(j * 64 + kt * 16 + lc) * 64 +
                                    kc * 32 + quad * 8];
      for (int kt = 0; kt < 4; ++kt)
        for (int q2 = 0; q2 < 2; ++q2)
          sacc[kt][q2] = __builtin_amdgcn_mfma_f32_16x16x32_bf16(
              kf[kt], qf[kc][q2], sacc[kt][q2], 0, 0, 0);
    }
    if (j == jmax) {  // causal partial tile
      for (int kt = 0; kt < 4; ++kt)
        for (int q2 = 0; q2 < 2; ++q2) {
          int rowrel = rowoff + q2 * 16 + lc;
          for (int r = 0; r < 4; ++r)
            if (kt * 16 + quad * 4 + r > rowrel) sacc[kt][q2][r] = -1.0e30f;
        }
    }
    for (int q2 = 0; q2 < 2; ++q2) {
      float vm = sacc[0][q2][0];
      for (int kt = 0; kt < 4; ++kt)
        for (int r = 0; r < 4; ++r) vm = fmaxf(vm, sacc[kt][q2][r]);
      vm = fmaxf(vm, __shfl_xor(vm, 16, 64));
      vm = fmaxf(vm, __shfl_xor(vm, 32, 64));
      float mn = fmaxf(m_[q2], vm);
      float alpha = exp2f(m_[q2] - mn);
      m_[q2] = mn;
      float rs = 0.0f;
      float p[4][4];
      for (int kt = 0; kt < 4; ++kt)
        for (int r = 0; r < 4; ++r) {
          p[kt][r] = exp2f(sacc[kt][q2][r] - mn);
          rs += p[kt][r];
        }
      rs += __shfl_xor(rs, 16, 64);
      rs += __shfl_xor(rs, 32, 64);
      l_[q2] = l_[q2] * alpha + rs;
      for (int mt = 0; mt < 4; ++mt) oacc[mt][q2] *= alpha;
      for (int kt = 0; kt < 4; ++kt) {
        uint2 pk = {pack2(p[kt][0], p[kt][1]), pack2(p[kt][2], p[kt][3])};
        *(uint2*)&Psw[(q2 * 16 + lc) * 64 + (((kt * 2 + (quad >> 1)) ^ l7) << 3) +
                      ((quad & 1) << 2)] = pk;
      }
    }
    __threadfence_block();
    for (int kc = 0; kc < 2; ++kc) {
      bf16x8 vf[4], pf[2];
      for (int mt = 0; mt < 4; ++mt)
        vf[mt] = *(const bf16x8*)&Vt[(long)(mt * 16 + lc) * 2048 + j * 64 +
                                     kc * 32 + quad * 8];
      for (int q2 = 0; q2 < 2; ++q2)
        pf[q2] = *(const bf16x8*)&Psw[(q2 * 16 + lc) * 64 +
                                      (((kc * 4 + quad) ^ l7) << 3)];
      for (int mt = 0; mt < 4; ++mt)
        for (int q2 = 0; q2 < 2; ++q2)
          oacc[mt][q2] = __builtin_amdgcn_mfma_f32_16x16x32_bf16(
              vf[mt], pf[q2], oacc[mt][q2], 0, 0, 0);
    }
    __threadfence_block();
  }

  // epilogue: O^T/l -> LDS (same swizzle) -> coalesced bf16 rows of ao
  for (int q2 = 0; q2 < 2; ++q2) {
    float linv = 1.0f / l_[q2];
    for (int mt = 0; mt < 4; ++mt) {
      uint2 pk = {pack2(oacc[mt][q2][0] * linv, oacc[mt][q2][1] * linv),
                  pack2(oacc[mt][q2][2] * linv, oacc[mt][q2][3] * linv)};
      *(uint2*)&Psw[(q2 * 16 + lc) * 64 + (((mt * 2 + (quad >> 1)) ^ l7) << 3) +
                    ((quad & 1) << 2)] = pk;
    }
  }
  __threadfence_block();
  {
    int r2 = lane >> 1;
    long mrow = (long)bidx * 2048 + qtbase + r2;
    for (int c = 0; c < 4; ++c) {
      int c8 = (lane & 1) * 4 + c;
      uint4 vv = *(const uint4*)&Psw[r2 * 64 + ((c8 ^ (r2 & 7)) << 3)];
      *(uint4*)&out[mrow * 1024 + h * 64 + c8 * 8] = vv;
    }
  }
}

extern "C" void kernel_launch(void* const* d_in, const int* in_sizes, int n_in,
                              void* d_out, int out_size, void* d_ws, size_t ws_size,
                              hipStream_t stream) {
  const float* x = nullptr;     // 4194304 elems
  const float* Wqkv = nullptr;  // 3145728 elems
  const float* Wo = nullptr;    // 1048576 elems
  for (int i = 0; i < n_in; ++i) {
    if (in_sizes[i] == 4194304) x = (const float*)d_in[i];
    else if (in_sizes[i] == 3145728) Wqkv = (const float*)d_in[i];
    else if (in_sizes[i] == 1048576) Wo = (const float*)d_in[i];
  }
  float* out = (float*)d_out;  // [4096,1024] fp32 (16 MiB)

  // Workspace (32 MiB) + d_out-as-scratch timeline (same as r13):
  ushort* qbuf = (ushort*)d_ws;
  ushort* kbuf = qbuf + 4194304;
  ushort* vbuf = kbuf + 4194304;
  ushort* vtb  = vbuf + 4194304;
  ushort* wqkvh = vtb;                 // [24..30) before vtrans
  ushort* woh  = qbuf;                 // [0..2) after attn
  ushort* ao   = vbuf;                 // aliases vbuf
  ushort* xh   = (ushort*)d_out;       // x_bf16 in d_out scratch

  conv_bf16<<<2048, 256, 0, stream>>>(x, xh, 524288);
  conv_bf16<<<1536, 256, 0, stream>>>(Wqkv, wqkvh, 393216);
  gemm_bt<<<768, 256, 0, stream>>>(xh, wqkvh, 24, qbuf, kbuf, vbuf, nullptr, 0);
  vtrans<<<dim3(32, 32), 256, 0, stream>>>(vbuf, vtb);
  attn_kernel<<<2048, 64, 0, stream>>>(qbuf, kbuf, vtb, ao);
  conv_bf16<<<512, 256, 0, stream>>>(Wo, woh, 131072);
  gemm_bt<<<256, 256, 0, stream>>>(ao, woh, 8, nullptr, nullptr, nullptr, out, 1);
}